// Round 21
// baseline (224.847 us; speedup 1.0000x reference)
//
#include <hip/hip_runtime.h>
#include <cstdint>
#include <cstddef>

typedef unsigned short u16;
typedef __attribute__((ext_vector_type(4))) float f32x4;
typedef __attribute__((ext_vector_type(8))) short bf16x8;
typedef __attribute__((ext_vector_type(4))) short bf16x4;

#define AS1 __attribute__((address_space(1)))
#define AS3 __attribute__((address_space(3)))
#define GLDS16(gp, lp) __builtin_amdgcn_global_load_lds((const AS1 void*)(gp), (AS3 void*)(lp), 16, 0, 0)

__device__ __forceinline__ float b2f(u16 u) {
  union { uint32_t i; float f; } v; v.i = ((uint32_t)u) << 16; return v.f;
}
__device__ __forceinline__ u16 f2b(float f) {
  union { float f; uint32_t i; } v; v.f = f;
  uint32_t r = v.i + 0x7fffu + ((v.i >> 16) & 1u);
  return (u16)(r >> 16);
}

// ---------------- prep: cvt(x) + transpose(Wqkv,PERM) + transpose(Wo) + doc -
__global__ __launch_bounds__(256) void prep(
    const float* __restrict__ x, u16* __restrict__ xb,
    const float* __restrict__ Wqkv, u16* __restrict__ WqkvT,
    const float* __restrict__ Wo, u16* __restrict__ WoT,
    const int* __restrict__ doc, int* __restrict__ ds) {
  __shared__ u16 t[32][33];
  int bid = blockIdx.x;
  if (bid < 8192) {  // cvt x -> bf16, float4 per thread
    int i = bid * 256 + threadIdx.x;
    float4 v = ((const float4*)x)[i];
    union { u16 s[4]; uint2 u; } o;
    o.s[0] = f2b(v.x); o.s[1] = f2b(v.y); o.s[2] = f2b(v.z); o.s[3] = f2b(v.w);
    ((uint2*)xb)[i] = o.u;
    return;
  }
  bid -= 8192;
  if (bid < 6144) {  // transpose Wqkv (R=2048, C=3072) with RoPE col-perm
    const int C = 3072, R = 2048;
    int bx = (bid % 96) * 32, by = (bid / 96) * 32;
    int tx = threadIdx.x & 31, ty = threadIdx.x >> 5;
#pragma unroll
    for (int i = 0; i < 4; ++i)
      t[ty + i * 8][tx] = f2b(Wqkv[(size_t)(by + ty + i * 8) * C + bx + tx]);
    __syncthreads();
#pragma unroll
    for (int i = 0; i < 4; ++i) {
      int c = bx + ty + i * 8;
      int cd = c;
      if (c < 2560) cd = (c & ~127) | (((c & 63) << 1) | ((c & 127) >> 6));
      WqkvT[(size_t)cd * R + by + tx] = t[tx][ty + i * 8];
    }
    return;
  }
  bid -= 6144;
  if (bid < 4096) {  // transpose Wo (2048 x 2048)
    const int C = 2048, R = 2048;
    int bx = (bid % 64) * 32, by = (bid / 64) * 32;
    int tx = threadIdx.x & 31, ty = threadIdx.x >> 5;
#pragma unroll
    for (int i = 0; i < 4; ++i)
      t[ty + i * 8][tx] = f2b(Wo[(size_t)(by + ty + i * 8) * C + bx + tx]);
    __syncthreads();
#pragma unroll
    for (int i = 0; i < 4; ++i)
      WoT[(size_t)(bx + ty + i * 8) * R + by + tx] = t[tx][ty + i * 8];
    return;
  }
  bid -= 4096;  // doc_starts: 16 blocks
  int i = bid * 256 + threadIdx.x;
  int b = i >> 11, s = i & 2047;
  int d = doc[i];
  if (s == 0 || doc[i - 1] != d) atomicMin(&ds[b * 4 + d], s);
}

// ======== gemm256: 256x256 tile, 8 waves (column strips), 8-phase ==========
// R20 schedule with the RACE FIX: tile t's bq (B frags) and phase-0 A frags
// are read ONLY AFTER q0's vmcnt+barrier (which drains tile t's 4 half-tiles:
// the oldest 8 of 12 outstanding loads). R20 read them before the wait ->
// intermittent corruption on replay. Phases 1-3 read early (covered by q0's
// wait). Stage stream at tile u: q0->(u+1).A1, q1->(u+1).B0, q2->(u+1).B1,
// q3->(u+2).A0; one vmcnt(4)/tile (vmcnt(0) at last tile).
// LDS [A|B][2dbuf][256x64] = 128KB, swizzle involution (conflicts=0 family).
// MODE 1: fp32 C. MODE 2: fused RoPE epilogue (permuted W_qkv cols).
template <int MODE>
__global__ __launch_bounds__(512, 2) void gemm256(
    const u16* __restrict__ A, const u16* __restrict__ Bt, void* __restrict__ Cv,
    int M, int N, int K,
    const float* __restrict__ sinb, const float* __restrict__ cosb,
    u16* __restrict__ Qp, u16* __restrict__ Kp, u16* __restrict__ Vtp) {
  __shared__ __align__(16) u16 L[4 * 256 * 64];  // A[2dbuf] then B[2dbuf]
  const int tid = threadIdx.x;                   // 0..511
  const int lane = tid & 63, wid = tid >> 6;     // 8 waves = 8 col strips
  const int g = lane >> 4, lr = lane & 15;
  const int gx = gridDim.x;
  const int nwg = gx * gridDim.y;
  int o = blockIdx.y * gx + blockIdx.x;
  o = (o & 7) * (nwg >> 3) + (o >> 3);
  const int bm0 = (o / gx) * 256, bn0 = (o % gx) * 256;
  f32x4 acc[16][2] = {};
  const int T = K >> 6;

#define STAGEH(d, h, isB, ktile) do {                                        \
    _Pragma("unroll") for (int j = 0; j < 2; ++j) {                          \
      int ci = j * 512 + tid;                                                \
      int hrow = ci >> 3;                                                    \
      int sch = (ci & 7) ^ (hrow & 7);                                       \
      const u16* src_ = ((isB) ? Bt + (size_t)(bn0 + (h) * 128 + hrow) * K   \
                               : A + (size_t)(bm0 + (h) * 128 + hrow) * K)   \
                        + (ktile) * 64 + sch * 8;                            \
      GLDS16(src_, (char*)L + (isB) * 65536 + (d) * 32768 + (h) * 16384 +    \
                       ci * 16);                                             \
    } } while (0)

  // phases 1..3: read A-quadrant early (data covered by q0's wait), stage,
  // barrier, MFMA, barrier.
#define PHASE(q, STG) do {                                                   \
    bf16x8 afr[4][2];                                                        \
    _Pragma("unroll") for (int m2 = 0; m2 < 4; ++m2)                         \
      _Pragma("unroll") for (int kh = 0; kh < 2; ++kh)                       \
        afr[m2][kh] = *(const bf16x8*)(LA_d + ((q) * 64 + m2 * 16 + lr) * 128\
                          + (((kh * 4 + g) ^ (lr & 7)) << 4));               \
    STG;                                                                     \
    __builtin_amdgcn_sched_barrier(0);                                       \
    __builtin_amdgcn_s_barrier();                                            \
    __builtin_amdgcn_sched_barrier(0);                                       \
    __builtin_amdgcn_s_setprio(1);                                           \
    _Pragma("unroll") for (int kh = 0; kh < 2; ++kh)                         \
      _Pragma("unroll") for (int m2 = 0; m2 < 4; ++m2)                       \
        _Pragma("unroll") for (int n = 0; n < 2; ++n)                        \
          acc[(q) * 4 + m2][n] = __builtin_amdgcn_mfma_f32_16x16x32_bf16(    \
              afr[m2][kh], bq[n][kh], acc[(q) * 4 + m2][n], 0, 0, 0);        \
    __builtin_amdgcn_s_setprio(0);                                           \
    __builtin_amdgcn_sched_barrier(0);                                       \
    __builtin_amdgcn_s_barrier();                                            \
  } while (0)

  // prologue: tile0's 4 halves + tile1's A0 (stream invariant)
  STAGEH(0, 0, 0, 0);
  STAGEH(0, 1, 0, 0);
  STAGEH(0, 0, 1, 0);
  STAGEH(0, 1, 1, 0);
  if (T > 1) STAGEH(1, 0, 0, 1);

  for (int t = 0; t < T; ++t) {
    const int d = t & 1;
    const char* LA_d = (const char*)L + d * 32768;
    const char* LB_d = (const char*)L + 65536 + d * 32768;
    // ---- phase 0 (special: wait BEFORE any tile-t LDS read) ----
    if (t + 1 < T) STAGEH(d ^ 1, 1, 0, t + 1);           // (t+1).A1
    if (t == T - 1) asm volatile("s_waitcnt vmcnt(0)" ::: "memory");
    else            asm volatile("s_waitcnt vmcnt(4)" ::: "memory");
    __builtin_amdgcn_sched_barrier(0);
    __builtin_amdgcn_s_barrier();
    __builtin_amdgcn_sched_barrier(0);
    // tile-t A and B now fully resident
    bf16x8 bq[2][2];
#pragma unroll
    for (int n = 0; n < 2; ++n)
#pragma unroll
      for (int kh = 0; kh < 2; ++kh)
        bq[n][kh] = *(const bf16x8*)(LB_d + (wid * 32 + n * 16 + lr) * 128 +
                                     (((kh * 4 + g) ^ (lr & 7)) << 4));
    {
      bf16x8 afr0[4][2];
#pragma unroll
      for (int m2 = 0; m2 < 4; ++m2)
#pragma unroll
        for (int kh = 0; kh < 2; ++kh)
          afr0[m2][kh] = *(const bf16x8*)(LA_d + (m2 * 16 + lr) * 128 +
                                          (((kh * 4 + g) ^ (lr & 7)) << 4));
      __builtin_amdgcn_s_setprio(1);
#pragma unroll
      for (int kh = 0; kh < 2; ++kh)
#pragma unroll
        for (int m2 = 0; m2 < 4; ++m2)
#pragma unroll
          for (int n = 0; n < 2; ++n)
            acc[m2][n] = __builtin_amdgcn_mfma_f32_16x16x32_bf16(
                afr0[m2][kh], bq[n][kh], acc[m2][n], 0, 0, 0);
      __builtin_amdgcn_s_setprio(0);
      __builtin_amdgcn_sched_barrier(0);
      __builtin_amdgcn_s_barrier();
    }
    // ---- phases 1..3 ----
    PHASE(1, { if (t + 1 < T) STAGEH(d ^ 1, 0, 1, t + 1); });  // (t+1).B0
    PHASE(2, { if (t + 1 < T) STAGEH(d ^ 1, 1, 1, t + 1); });  // (t+1).B1
    PHASE(3, { if (t + 2 < T) STAGEH(d, 0, 0, t + 2); });      // (t+2).A0
  }
#undef PHASE
#undef STAGEH

  if (MODE == 1) {
#pragma unroll
    for (int mq = 0; mq < 16; ++mq)
#pragma unroll
      for (int r = 0; r < 4; ++r) {
        int row = bm0 + (mq >> 2) * 64 + (mq & 3) * 16 + g * 4 + r;
        float* cp2 = (float*)Cv + (size_t)row * N + bn0 + wid * 32 + lr;
#pragma unroll
        for (int n = 0; n < 2; ++n) cp2[n * 16] = acc[mq][n][r];
      }
  } else {
    // fused RoPE + split epilogue (cols are permuted: pairs adjacent)
#pragma unroll
    for (int mq = 0; mq < 16; ++mq)
#pragma unroll
      for (int r = 0; r < 4; ++r) {
        int row = bm0 + (mq >> 2) * 64 + (mq & 3) * 16 + g * 4 + r;
        int b = row >> 11, s = row & 2047;
#pragma unroll
        for (int n = 0; n < 2; ++n) {
          float val = acc[mq][n][r];
          float par = __shfl_xor(val, 1, 64);
          int c = bn0 + wid * 32 + n * 16 + lr;
          if (c < 2560) {
            int hi = c & 1;
            int d2 = (c & 127) >> 1;
            float sv = sinb[s * 64 + d2], cvv = cosb[s * 64 + d2];
            float x1 = hi ? par : val;
            float x2 = hi ? val : par;
            float ov = hi ? (x2 * cvv + x1 * sv) : (x1 * cvv - x2 * sv);
            if (c < 2048) {
              int hh = c >> 7;
              Qp[((size_t)(b * 16 + hh) * 2048 + s) * 128 + d2 + 64 * hi] = f2b(ov);
            } else {
              int g2 = (c - 2048) >> 7;
              Kp[((size_t)(b * 4 + g2) * 2048 + s) * 128 + d2 + 64 * hi] = f2b(ov);
            }
          } else {
            int off2 = c - 2560;
            int g2 = off2 >> 7, d2 = off2 & 127;
            Vtp[((size_t)(b * 4 + g2) * 128 + d2) * 2048 + s] = f2b(val);
          }
        }
      }
  }
}

// ---------------- Flash attention, swapped-QK + K double-buffer ------------
// (unchanged from R14)
__global__ __launch_bounds__(256) void attn_fwd(
    const u16* __restrict__ Q, const u16* __restrict__ Kb,
    const u16* __restrict__ Vt, const int* __restrict__ dstab,
    u16* __restrict__ Out) {
  const int qb = 31 - blockIdx.x;  // longest blocks first
  const int h = blockIdx.y, b = blockIdx.z;
  const int gkv = h >> 2;
  const int tid = threadIdx.x, wv = tid >> 6, lane = tid & 63;
  const int g = lane >> 4, lr = lane & 15;
  const float scale = 0.08838834764831845f;  // 1/sqrt(128)
  __shared__ __align__(16) u16 Kl[2][32 * 128];  // dbuf, swizzled, 16KB
  __shared__ __align__(16) u16 Vl[128 * 40];     // 80B rows, 10KB
  const u16* Kbase = Kb + (size_t)(b * 4 + gkv) * 2048 * 128;
  const u16* Vbase = Vt + (size_t)(b * 4 + gkv) * 128 * 2048;
  const int b2048 = b * 2048;
  const int st1 = dstab[b * 4 + 1], st2 = dstab[b * 4 + 2], st3 = dstab[b * 4 + 3];

  const int q0w = qb * 64 + wv * 16;
  const int q = q0w + lr;  // this lane's q row
  const int labq = (q >= st1) + (q >= st2) + (q >= st3);
  const u16* qp = Q + ((size_t)(b * 16 + h) * 2048 + q) * 128;
  bf16x8 qf[4];
#pragma unroll
  for (int c = 0; c < 4; ++c) qf[c] = *(const bf16x8*)(qp + c * 32 + g * 8);
  f32x4 acc[8] = {};
  float lsum = 0.f;
  const int qfirst = qb * 64;
  int kv_lo = 0;
  if (st1 <= qfirst) kv_lo = st1;
  if (st2 <= qfirst) kv_lo = st2;
  if (st3 <= qfirst) kv_lo = st3;
  kv_lo &= ~31;
  const int kv_end = qb * 64 + 64;
  const int nt = (kv_end - kv_lo) >> 5;

  const int kr0 = tid >> 4, j0 = tid & 15;
  const int kr1 = (tid + 256) >> 4, j1 = tid & 15;
  const size_t koff0 = (size_t)kr0 * 128 + ((j0 ^ (kr0 & 7)) << 3);
  const size_t koff1 = (size_t)kr1 * 128 + ((j1 ^ (kr1 & 7)) << 3);
  const int vd0 = tid >> 2, vc0 = tid & 3;
  const int vd1 = (tid + 256) >> 2, vc1 = tid & 3;

#define STAGEK(c, kv0_)                                                   \
  do {                                                                    \
    GLDS16(Kbase + (size_t)(kv0_) * 128 + koff0, (char*)Kl[c] + tid * 16);\
    GLDS16(Kbase + (size_t)(kv0_) * 128 + koff1,                          \
           (char*)Kl[c] + (tid + 256) * 16);                              \
  } while (0)

  STAGEK(0, kv_lo);
  int kv0 = kv_lo;
  for (int i = 0; i < nt; ++i, kv0 += 32) {
    const int cbuf = i & 1;
    bf16x8 vreg0 = *(const bf16x8*)(Vbase + (size_t)vd0 * 2048 + kv0 + vc0 * 8);
    bf16x8 vreg1 = *(const bf16x8*)(Vbase + (size_t)vd1 * 2048 + kv0 + vc1 * 8);
    __builtin_amdgcn_sched_barrier(0);
    if (i + 1 < nt) STAGEK(cbuf ^ 1, kv0 + 32);
    __builtin_amdgcn_sched_barrier(0);
    *(bf16x8*)((char*)Vl + vd0 * 80 + vc0 * 16) = vreg0;
    *(bf16x8*)((char*)Vl + vd1 * 80 + vc1 * 16) = vreg1;
    asm volatile("s_waitcnt vmcnt(2) lgkmcnt(0)" ::: "memory");
    __builtin_amdgcn_s_barrier();
    __builtin_amdgcn_sched_barrier(0);
    f32x4 s[2] = {{0.f, 0.f, 0.f, 0.f}, {0.f, 0.f, 0.f, 0.f}};
    __builtin_amdgcn_s_setprio(1);
#pragma unroll
    for (int c = 0; c < 4; ++c) {
      int chnk = ((c * 4 + g) ^ (lr & 7)) << 4;
      bf16x8 k0 = *(const bf16x8*)((const char*)Kl[cbuf] + lr * 256 + chnk);
      s[0] = __builtin_amdgcn_mfma_f32_16x16x32_bf16(k0, qf[c], s[0], 0, 0, 0);
      bf16x8 k1 = *(const bf16x8*)((const char*)Kl[cbuf] + (16 + lr) * 256 + chnk);
      s[1] = __builtin_amdgcn_mfma_f32_16x16x32_bf16(k1, qf[c], s[1], 0, 0, 0);
    }
    __builtin_amdgcn_s_setprio(0);
    bf16x4 pf[2];
#pragma unroll
    for (int hf = 0; hf < 2; ++hf) {
#pragma unroll
      for (int r = 0; r < 4; ++r) {
        int kv = kv0 + 16 * hf + 4 * g + r;
        int lab = (kv >= st1) + (kv >= st2) + (kv >= st3);
        float sv = (kv <= q && lab == labq) ? s[hf][r] * scale - 8.0f : -INFINITY;
        float p = __expf(sv);
        lsum += p;
        pf[hf][r] = (short)f2b(p);
      }
    }
    __builtin_amdgcn_s_setprio(1);
#pragma unroll
    for (int chn = 0; chn < 8; ++chn) {
      const u16* vrow = (const u16*)Vl + (chn * 16 + lr) * 40 + 4 * g;
      bf16x4 v0 = *(const bf16x4*)(vrow);
      bf16x4 v1 = *(const bf16x4*)(vrow + 16);
      acc[chn] = __builtin_amdgcn_mfma_f32_16x16x16bf16_1k(pf[0], v0, acc[chn], 0, 0, 0);
      acc[chn] = __builtin_amdgcn_mfma_f32_16x16x16bf16_1k(pf[1], v1, acc[chn], 0, 0, 0);
    }
    __builtin_amdgcn_s_setprio(0);
    __builtin_amdgcn_s_barrier();
    __builtin_amdgcn_sched_barrier(0);
  }
#undef STAGEK
  lsum += __shfl_xor(lsum, 16, 64);
  lsum += __shfl_xor(lsum, 32, 64);
#pragma unroll
  for (int r = 0; r < 4; ++r) {
    float inv = 1.0f / __shfl(lsum, 4 * g + r, 64);
    int sq = q0w + 4 * g + r;
    u16* op = Out + ((size_t)b2048 + sq) * 2048 + h * 128 + lr;
#pragma unroll
    for (int chn = 0; chn < 8; ++chn) op[chn * 16] = f2b(acc[chn][r] * inv);
  }
}

extern "C" void kernel_launch(void* const* d_in, const int* in_sizes, int n_in,
                              void* d_out, int out_size, void* d_ws, size_t ws_size,
                              hipStream_t stream) {
  const float* x = (const float*)d_in[0];
  const float* sinb = (const float*)d_in[1];
  const float* cosb = (const float*)d_in[2];
  const int* doc = (const int*)d_in[3];
  const float* Wqkv = (const float*)d_in[4];
  const float* Wo = (const float*)d_in[5];

  u16* ws = (u16*)d_ws;
  u16* xb = ws;                              // 8,388,608
  u16* attout = xb;                          // reuse after GEMM1
  u16* WqkvT = ws + 8388608;                 // 6,291,456
  u16* WoT = WqkvT + 6291456;                // 4,194,304
  u16* Qb = WoT + 4194304;                   // 8,388,608
  u16* Kb = Qb + 8388608;                    // 2,097,152
  u16* Vt = Kb + 2097152;                    // 2,097,152
  int* dstab = (int*)(Vt + 2097152);         // 8 ints

  hipMemsetAsync(dstab, 0x7f, 8 * sizeof(int), stream);
  prep<<<8192 + 6144 + 4096 + 16, 256, 0, stream>>>(
      x, xb, Wqkv, WqkvT, Wo, WoT, doc, dstab);
  gemm256<2><<<dim3(3072 / 256, 4096 / 256), 512, 0, stream>>>(
      xb, WqkvT, nullptr, 4096, 3072, 2048, sinb, cosb, Qb, Kb, Vt);
  attn_fwd<<<dim3(32, 16, 2), 256, 0, stream>>>(Qb, Kb, Vt, dstab, attout);
  gemm256<1><<<dim3(2048 / 256, 4096 / 256), 512, 0, stream>>>(
      attout, WoT, (float*)d_out, 4096, 2048, 2048,
      nullptr, nullptr, nullptr, nullptr, nullptr);
}

// Round 22
// 179.684 us; speedup vs baseline: 1.2514x; 1.2514x over previous
//
#include <hip/hip_runtime.h>
#include <cstdint>
#include <cstddef>

typedef unsigned short u16;
typedef __attribute__((ext_vector_type(4))) float f32x4;
typedef __attribute__((ext_vector_type(8))) short bf16x8;
typedef __attribute__((ext_vector_type(4))) short bf16x4;

#define AS1 __attribute__((address_space(1)))
#define AS3 __attribute__((address_space(3)))
#define GLDS16(gp, lp) __builtin_amdgcn_global_load_lds((const AS1 void*)(gp), (AS3 void*)(lp), 16, 0, 0)

__device__ __forceinline__ float b2f(u16 u) {
  union { uint32_t i; float f; } v; v.i = ((uint32_t)u) << 16; return v.f;
}
__device__ __forceinline__ u16 f2b(float f) {
  union { float f; uint32_t i; } v; v.f = f;
  uint32_t r = v.i + 0x7fffu + ((v.i >> 16) & 1u);
  return (u16)(r >> 16);
}

// ---------------- prep: cvt(x) + transpose(Wqkv,PERM) + transpose(Wo) + doc -
__global__ __launch_bounds__(256) void prep(
    const float* __restrict__ x, u16* __restrict__ xb,
    const float* __restrict__ Wqkv, u16* __restrict__ WqkvT,
    const float* __restrict__ Wo, u16* __restrict__ WoT,
    const int* __restrict__ doc, int* __restrict__ ds) {
  __shared__ u16 t[32][33];
  int bid = blockIdx.x;
  if (bid < 8192) {  // cvt x -> bf16, float4 per thread
    int i = bid * 256 + threadIdx.x;
    float4 v = ((const float4*)x)[i];
    union { u16 s[4]; uint2 u; } o;
    o.s[0] = f2b(v.x); o.s[1] = f2b(v.y); o.s[2] = f2b(v.z); o.s[3] = f2b(v.w);
    ((uint2*)xb)[i] = o.u;
    return;
  }
  bid -= 8192;
  if (bid < 6144) {  // transpose Wqkv (R=2048, C=3072) with RoPE col-perm
    const int C = 3072, R = 2048;
    int bx = (bid % 96) * 32, by = (bid / 96) * 32;
    int tx = threadIdx.x & 31, ty = threadIdx.x >> 5;
#pragma unroll
    for (int i = 0; i < 4; ++i)
      t[ty + i * 8][tx] = f2b(Wqkv[(size_t)(by + ty + i * 8) * C + bx + tx]);
    __syncthreads();
#pragma unroll
    for (int i = 0; i < 4; ++i) {
      int c = bx + ty + i * 8;
      int cd = c;
      if (c < 2560) cd = (c & ~127) | (((c & 63) << 1) | ((c & 127) >> 6));
      WqkvT[(size_t)cd * R + by + tx] = t[tx][ty + i * 8];
    }
    return;
  }
  bid -= 6144;
  if (bid < 4096) {  // transpose Wo (2048 x 2048)
    const int C = 2048, R = 2048;
    int bx = (bid % 64) * 32, by = (bid / 64) * 32;
    int tx = threadIdx.x & 31, ty = threadIdx.x >> 5;
#pragma unroll
    for (int i = 0; i < 4; ++i)
      t[ty + i * 8][tx] = f2b(Wo[(size_t)(by + ty + i * 8) * C + bx + tx]);
    __syncthreads();
#pragma unroll
    for (int i = 0; i < 4; ++i)
      WoT[(size_t)(bx + ty + i * 8) * R + by + tx] = t[tx][ty + i * 8];
    return;
  }
  bid -= 4096;  // doc_starts: 16 blocks
  int i = bid * 256 + threadIdx.x;
  int b = i >> 11, s = i & 2047;
  int d = doc[i];
  if (s == 0 || doc[i - 1] != d) atomicMin(&ds[b * 4 + d], s);
}

// ---------------- GEMM (R10/R14 inner loop; KSTEP-templated) ----------------
// 128x128 tile, 4 waves (2x2), 16x16x32 MFMA. LDS XOR-swizzled (conflicts=0,
// R10-measured). XCD-aware block swizzle.
// KSTEP=64: 32KB LDS (3 blocks/CU at gemm1's 768-block grid).
// KSTEP=128: 64KB LDS, halves barrier count (neutral-measured; kept for
//   gemm2 where grid caps at 2 blocks/CU anyway).
// MODE 1: fp32 C store. MODE 2: fused RoPE epilogue (permuted W_qkv cols).
template <int MODE, int KSTEP>
__global__ __launch_bounds__(256) void gemm_bt(
    const u16* __restrict__ A, const u16* __restrict__ Bt, void* __restrict__ Cv,
    int M, int N, int K,
    const float* __restrict__ sinb, const float* __restrict__ cosb,
    u16* __restrict__ Qp, u16* __restrict__ Kp, u16* __restrict__ Vtp) {
  __shared__ __align__(16) u16 lA[(KSTEP / 64) * 128 * 64];
  __shared__ __align__(16) u16 lB[(KSTEP / 64) * 128 * 64];
  const int tid = threadIdx.x;
  const int lane = tid & 63, wv = tid >> 6;
  const int g = lane >> 4, lr = lane & 15;
  const int wr = wv >> 1, wc = wv & 1;
  const int gx = gridDim.x;
  const int nwg = gx * gridDim.y;
  int o = blockIdx.y * gx + blockIdx.x;
  o = (o & 7) * (nwg >> 3) + (o >> 3);
  const int bm0 = (o / gx) * 128, bn0 = (o % gx) * 128;
  f32x4 acc[4][4] = {};
  const int srow = tid >> 3;                  // 0..31 (+32 per issue)
  const int schunk = (tid & 7) ^ (srow & 7);  // inverse-swizzled source chunk
  const u16* ga = A + (size_t)(bm0 + srow) * K + schunk * 8;
  const u16* gb = Bt + (size_t)(bn0 + srow) * K + schunk * 8;
  for (int kt = 0; kt < K; kt += KSTEP) {
#pragma unroll
    for (int sub = 0; sub < KSTEP / 64; ++sub)
#pragma unroll
      for (int it = 0; it < 4; ++it) {
        GLDS16(ga + (size_t)(it * 32) * K + kt + sub * 64,
               (char*)lA + sub * 16384 + (it * 256 + tid) * 16);
        GLDS16(gb + (size_t)(it * 32) * K + kt + sub * 64,
               (char*)lB + sub * 16384 + (it * 256 + tid) * 16);
      }
    __syncthreads();
#pragma unroll
    for (int sub = 0; sub < KSTEP / 64; ++sub) {
      const char* ra = (const char*)lA + sub * 16384;
      const char* rb = (const char*)lB + sub * 16384;
      bf16x8 af[2][4], bfr[2][4];
#pragma unroll
      for (int kh = 0; kh < 2; ++kh) {
        const int chnk = ((kh * 4 + g) ^ (lr & 7)) << 4;
#pragma unroll
        for (int m = 0; m < 4; ++m)
          af[kh][m] = *(const bf16x8*)(ra + (wr * 64 + m * 16 + lr) * 128 + chnk);
#pragma unroll
        for (int n = 0; n < 4; ++n)
          bfr[kh][n] = *(const bf16x8*)(rb + (wc * 64 + n * 16 + lr) * 128 + chnk);
      }
      __builtin_amdgcn_s_setprio(1);
#pragma unroll
      for (int kh = 0; kh < 2; ++kh)
#pragma unroll
        for (int m = 0; m < 4; ++m)
#pragma unroll
          for (int n = 0; n < 4; ++n)
            acc[m][n] = __builtin_amdgcn_mfma_f32_16x16x32_bf16(af[kh][m], bfr[kh][n], acc[m][n], 0, 0, 0);
      __builtin_amdgcn_s_setprio(0);
    }
    __syncthreads();
  }
  if (MODE == 1) {
#pragma unroll
    for (int m = 0; m < 4; ++m)
#pragma unroll
      for (int r = 0; r < 4; ++r) {
        int row = bm0 + wr * 64 + m * 16 + g * 4 + r;
        float* cp2 = (float*)Cv + (size_t)row * N + bn0 + wc * 64 + lr;
#pragma unroll
        for (int n = 0; n < 4; ++n) cp2[n * 16] = acc[m][n][r];
      }
  } else {
    // fused RoPE + split epilogue (cols are permuted: pairs adjacent)
#pragma unroll
    for (int m = 0; m < 4; ++m)
#pragma unroll
      for (int r = 0; r < 4; ++r) {
        int row = bm0 + wr * 64 + m * 16 + g * 4 + r;
        int b = row >> 11, s = row & 2047;
#pragma unroll
        for (int n = 0; n < 4; ++n) {
          float val = acc[m][n][r];
          float par = __shfl_xor(val, 1, 64);
          int c = bn0 + wc * 64 + n * 16 + lr;
          if (c < 2560) {
            int hi = c & 1;
            int d = (c & 127) >> 1;
            float sv = sinb[s * 64 + d], cvv = cosb[s * 64 + d];
            float x1 = hi ? par : val;
            float x2 = hi ? val : par;
            float ov = hi ? (x2 * cvv + x1 * sv) : (x1 * cvv - x2 * sv);
            if (c < 2048) {
              int hh = c >> 7;
              Qp[((size_t)(b * 16 + hh) * 2048 + s) * 128 + d + 64 * hi] = f2b(ov);
            } else {
              int g2 = (c - 2048) >> 7;
              Kp[((size_t)(b * 4 + g2) * 2048 + s) * 128 + d + 64 * hi] = f2b(ov);
            }
          } else {
            int off2 = c - 2560;
            int g2 = off2 >> 7, d = off2 & 127;
            Vtp[((size_t)(b * 4 + g2) * 128 + d) * 2048 + s] = f2b(val);
          }
        }
      }
  }
}

// ---------------- Flash attention, swapped-QK + K double-buffer ------------
// (unchanged from R14)
__global__ __launch_bounds__(256) void attn_fwd(
    const u16* __restrict__ Q, const u16* __restrict__ Kb,
    const u16* __restrict__ Vt, const int* __restrict__ dstab,
    u16* __restrict__ Out) {
  const int qb = 31 - blockIdx.x;  // longest blocks first
  const int h = blockIdx.y, b = blockIdx.z;
  const int gkv = h >> 2;
  const int tid = threadIdx.x, wv = tid >> 6, lane = tid & 63;
  const int g = lane >> 4, lr = lane & 15;
  const float scale = 0.08838834764831845f;  // 1/sqrt(128)
  __shared__ __align__(16) u16 Kl[2][32 * 128];  // dbuf, swizzled, 16KB
  __shared__ __align__(16) u16 Vl[128 * 40];     // 80B rows, 10KB
  const u16* Kbase = Kb + (size_t)(b * 4 + gkv) * 2048 * 128;
  const u16* Vbase = Vt + (size_t)(b * 4 + gkv) * 128 * 2048;
  const int b2048 = b * 2048;
  const int st1 = dstab[b * 4 + 1], st2 = dstab[b * 4 + 2], st3 = dstab[b * 4 + 3];

  const int q0w = qb * 64 + wv * 16;
  const int q = q0w + lr;  // this lane's q row
  const int labq = (q >= st1) + (q >= st2) + (q >= st3);
  const u16* qp = Q + ((size_t)(b * 16 + h) * 2048 + q) * 128;
  bf16x8 qf[4];
#pragma unroll
  for (int c = 0; c < 4; ++c) qf[c] = *(const bf16x8*)(qp + c * 32 + g * 8);
  f32x4 acc[8] = {};
  float lsum = 0.f;
  const int qfirst = qb * 64;
  int kv_lo = 0;
  if (st1 <= qfirst) kv_lo = st1;
  if (st2 <= qfirst) kv_lo = st2;
  if (st3 <= qfirst) kv_lo = st3;
  kv_lo &= ~31;
  const int kv_end = qb * 64 + 64;
  const int nt = (kv_end - kv_lo) >> 5;

  const int kr0 = tid >> 4, j0 = tid & 15;
  const int kr1 = (tid + 256) >> 4, j1 = tid & 15;
  const size_t koff0 = (size_t)kr0 * 128 + ((j0 ^ (kr0 & 7)) << 3);
  const size_t koff1 = (size_t)kr1 * 128 + ((j1 ^ (kr1 & 7)) << 3);
  const int vd0 = tid >> 2, vc0 = tid & 3;
  const int vd1 = (tid + 256) >> 2, vc1 = tid & 3;

#define STAGEK(c, kv0_)                                                   \
  do {                                                                    \
    GLDS16(Kbase + (size_t)(kv0_) * 128 + koff0, (char*)Kl[c] + tid * 16);\
    GLDS16(Kbase + (size_t)(kv0_) * 128 + koff1,                          \
           (char*)Kl[c] + (tid + 256) * 16);                              \
  } while (0)

  STAGEK(0, kv_lo);
  int kv0 = kv_lo;
  for (int i = 0; i < nt; ++i, kv0 += 32) {
    const int cbuf = i & 1;
    bf16x8 vreg0 = *(const bf16x8*)(Vbase + (size_t)vd0 * 2048 + kv0 + vc0 * 8);
    bf16x8 vreg1 = *(const bf16x8*)(Vbase + (size_t)vd1 * 2048 + kv0 + vc1 * 8);
    __builtin_amdgcn_sched_barrier(0);
    if (i + 1 < nt) STAGEK(cbuf ^ 1, kv0 + 32);
    __builtin_amdgcn_sched_barrier(0);
    *(bf16x8*)((char*)Vl + vd0 * 80 + vc0 * 16) = vreg0;
    *(bf16x8*)((char*)Vl + vd1 * 80 + vc1 * 16) = vreg1;
    asm volatile("s_waitcnt vmcnt(2) lgkmcnt(0)" ::: "memory");
    __builtin_amdgcn_s_barrier();
    __builtin_amdgcn_sched_barrier(0);
    f32x4 s[2] = {{0.f, 0.f, 0.f, 0.f}, {0.f, 0.f, 0.f, 0.f}};
    __builtin_amdgcn_s_setprio(1);
#pragma unroll
    for (int c = 0; c < 4; ++c) {
      int chnk = ((c * 4 + g) ^ (lr & 7)) << 4;
      bf16x8 k0 = *(const bf16x8*)((const char*)Kl[cbuf] + lr * 256 + chnk);
      s[0] = __builtin_amdgcn_mfma_f32_16x16x32_bf16(k0, qf[c], s[0], 0, 0, 0);
      bf16x8 k1 = *(const bf16x8*)((const char*)Kl[cbuf] + (16 + lr) * 256 + chnk);
      s[1] = __builtin_amdgcn_mfma_f32_16x16x32_bf16(k1, qf[c], s[1], 0, 0, 0);
    }
    __builtin_amdgcn_s_setprio(0);
    bf16x4 pf[2];
#pragma unroll
    for (int hf = 0; hf < 2; ++hf) {
#pragma unroll
      for (int r = 0; r < 4; ++r) {
        int kv = kv0 + 16 * hf + 4 * g + r;
        int lab = (kv >= st1) + (kv >= st2) + (kv >= st3);
        float sv = (kv <= q && lab == labq) ? s[hf][r] * scale - 8.0f : -INFINITY;
        float p = __expf(sv);
        lsum += p;
        pf[hf][r] = (short)f2b(p);
      }
    }
    __builtin_amdgcn_s_setprio(1);
#pragma unroll
    for (int chn = 0; chn < 8; ++chn) {
      const u16* vrow = (const u16*)Vl + (chn * 16 + lr) * 40 + 4 * g;
      bf16x4 v0 = *(const bf16x4*)(vrow);
      bf16x4 v1 = *(const bf16x4*)(vrow + 16);
      acc[chn] = __builtin_amdgcn_mfma_f32_16x16x16bf16_1k(pf[0], v0, acc[chn], 0, 0, 0);
      acc[chn] = __builtin_amdgcn_mfma_f32_16x16x16bf16_1k(pf[1], v1, acc[chn], 0, 0, 0);
    }
    __builtin_amdgcn_s_setprio(0);
    __builtin_amdgcn_s_barrier();
    __builtin_amdgcn_sched_barrier(0);
  }
#undef STAGEK
  lsum += __shfl_xor(lsum, 16, 64);
  lsum += __shfl_xor(lsum, 32, 64);
#pragma unroll
  for (int r = 0; r < 4; ++r) {
    float inv = 1.0f / __shfl(lsum, 4 * g + r, 64);
    int sq = q0w + 4 * g + r;
    u16* op = Out + ((size_t)b2048 + sq) * 2048 + h * 128 + lr;
#pragma unroll
    for (int chn = 0; chn < 8; ++chn) op[chn * 16] = f2b(acc[chn][r] * inv);
  }
}

extern "C" void kernel_launch(void* const* d_in, const int* in_sizes, int n_in,
                              void* d_out, int out_size, void* d_ws, size_t ws_size,
                              hipStream_t stream) {
  const float* x = (const float*)d_in[0];
  const float* sinb = (const float*)d_in[1];
  const float* cosb = (const float*)d_in[2];
  const int* doc = (const int*)d_in[3];
  const float* Wqkv = (const float*)d_in[4];
  const float* Wo = (const float*)d_in[5];

  u16* ws = (u16*)d_ws;
  u16* xb = ws;                              // 8,388,608
  u16* attout = xb;                          // reuse after GEMM1
  u16* WqkvT = ws + 8388608;                 // 6,291,456
  u16* WoT = WqkvT + 6291456;                // 4,194,304
  u16* Qb = WoT + 4194304;                   // 8,388,608
  u16* Kb = Qb + 8388608;                    // 2,097,152
  u16* Vt = Kb + 2097152;                    // 2,097,152
  int* dstab = (int*)(Vt + 2097152);         // 8 ints

  hipMemsetAsync(dstab, 0x7f, 8 * sizeof(int), stream);
  prep<<<8192 + 6144 + 4096 + 16, 256, 0, stream>>>(
      x, xb, Wqkv, WqkvT, Wo, WoT, doc, dstab);
  gemm_bt<2, 64><<<dim3(3072 / 128, 4096 / 128), 256, 0, stream>>>(
      xb, WqkvT, nullptr, 4096, 3072, 2048, sinb, cosb, Qb, Kb, Vt);
  attn_fwd<<<dim3(32, 16, 2), 256, 0, stream>>>(Qb, Kb, Vt, dstab, attout);
  gemm_bt<1, 128><<<dim3(2048 / 128, 4096 / 128), 256, 0, stream>>>(
      attout, WoT, (float*)d_out, 4096, 2048, 2048,
      nullptr, nullptr, nullptr, nullptr, nullptr);
}